// Round 10
// baseline (105.299 us; speedup 1.0000x reference)
//
#include <hip/hip_runtime.h>
#include <stdint.h>
#include <stddef.h>

// MambaMesh random-walk + gather-recenter.  R10: split pipes — rows on VMEM,
// visited bitmap on DS.
// PRNG (bit-exact vs JAX partitionable Threefry, verified R1-R9, absmax 0.0):
//   split(key,n)[j]        = threefry2x32(key; 0, j)   (both output words)
//   random_bits(key,32,()) = xor-fold of threefry2x32(key; 0, 0)
// R9 lesson: walk became LDS-pipe-throughput-bound: 11 DS ops/iter x 5.8cyc
// x 16 waves/CU ~= 1000 cyc/iter (ds_read_b32 ~5.8cyc, m134). R8 proved row
// source latency (HBM vs LDS) doesn't matter. R10: rows via global VMEM
// speculative triplet (R5-verified), DS carries ONLY the bitmap (3 reads +
// 1 write /iter), code fetch via v_readlane (no DS), no table staging (its
// u16 writes were the 245k bank conflicts). Bitmap now covers N<=65536.
//   block = 1024 thr = 16 waves = 16 walks; 256 blocks = 1/CU; ONE barrier.
//   chains: wave 0, lane-parallel, dep-bound ~8us (known floor).

namespace {

__device__ __forceinline__ uint32_t rotl32(uint32_t x, int r) {
  return (x << r) | (x >> (32 - r));
}

// Threefry-2x32, 20 rounds — exactly JAX's threefry2x32_p.
__device__ __forceinline__ void tf2x32(uint32_t ka, uint32_t kb,
                                       uint32_t x0, uint32_t x1,
                                       uint32_t& o0, uint32_t& o1) {
  const uint32_t kc = ka ^ kb ^ 0x1BD11BDAu;
  x0 += ka; x1 += kb;
#define TF_R4(r0, r1, r2, r3)                          \
  x0 += x1; x1 = rotl32(x1, r0); x1 ^= x0;             \
  x0 += x1; x1 = rotl32(x1, r1); x1 ^= x0;             \
  x0 += x1; x1 = rotl32(x1, r2); x1 ^= x0;             \
  x0 += x1; x1 = rotl32(x1, r3); x1 ^= x0;
  TF_R4(13, 15, 26, 6)  x0 += kb; x1 += kc + 1u;
  TF_R4(17, 29, 16, 24) x0 += kc; x1 += ka + 2u;
  TF_R4(13, 15, 26, 6)  x0 += ka; x1 += kb + 3u;
  TF_R4(17, 29, 16, 24) x0 += kb; x1 += kc + 4u;
  TF_R4(13, 15, 26, 6)  x0 += kc; x1 += ka + 5u;
#undef TF_R4
  o0 = x0; o1 = x1;
}

// (hi, lo) bits of jax.random.randint(key, (), 0, span): span-independent.
__device__ __forceinline__ void randbits(uint32_t ka, uint32_t kb,
                                         uint32_t& hi, uint32_t& lo) {
  uint32_t s0a, s0b, s1a, s1b, h0, h1;
  tf2x32(ka, kb, 0u, 0u, s0a, s0b);   // split(key)[0]
  tf2x32(ka, kb, 0u, 1u, s1a, s1b);   // split(key)[1]
  tf2x32(s0a, s0b, 0u, 0u, h0, h1);
  hi = h0 ^ h1;
  tf2x32(s1a, s1b, 0u, 0u, h0, h1);
  lo = h0 ^ h1;
}

__device__ __forceinline__ uint32_t r_generic(uint32_t hi, uint32_t lo,
                                              uint32_t span) {
  uint32_t mult = 65536u % span;
  mult = (mult * mult) % span;
  return ((hi % span) * mult + (lo % span)) % span;
}

// pick code: r3 (span=3 result) in bits 0..1, r2 (span=2 result) in bit 2.
__device__ __forceinline__ uint32_t pick_code(uint32_t hi, uint32_t lo) {
  return ((hi % 3u + lo % 3u) % 3u) | ((lo & 1u) << 2);
}

constexpr int WPB = 16;       // walks per block (one per wave; 1024 threads)
constexpr int CH = 64;        // cached chain length (covers seq_len 63)
constexpr int KSTRIDE = 65;   // keysL stride in uint2 (breaks bank alias)
constexpr int VISW = 2048;    // bitmap words per walk -> covers N <= 65536

__global__ __launch_bounds__(1024) void walk_kernel(
    const float* __restrict__ xyz, const int* __restrict__ nbrs,
    const int* __restrict__ centers, const int* __restrict__ n_faces_p,
    const int* __restrict__ seq_len_p, float* __restrict__ out,
    int s0, int num_walks, int Lp1) {
  // Static LDS: bitmaps 131,072 B + keys 8,320 B = 139,392 B (< 163,840).
  __shared__ uint32_t visL[WPB * VISW];
  __shared__ uint2 keysL[WPB * KSTRIDE];

  const int tid = threadIdx.x;
  const int wv = tid >> 6, lane = tid & 63;
  const int w0 = blockIdx.x * WPB;
  if (w0 >= num_walks) return;             // block-uniform
  const int w = w0 + wv;
  const bool active = (w < num_walks);

  const int N = *n_faces_p;
  const int L = *seq_len_p;
  const int B = s0 / (3 * N);
  const int G = num_walks / B;
  const bool bm_ok = (N <= VISW * 32);     // grid-uniform

  const int bb = (active ? w : w0) / G;    // per-wave batch (no straddle issue)
  const int* __restrict__ nb   = nbrs + (size_t)bb * N * 3;
  const float* __restrict__ xb = xyz + (size_t)bb * N * 3;

  const int f0 = active ? centers[w] : 0;
  // First row in flight through the whole chain phase.
  int3 row = *reinterpret_cast<const int3*>(nb + 3 * (size_t)f0);

  // Zero own bitmap (wave-local, in-order DS; no barrier needed for own use).
  uint32_t* __restrict__ visW = visL + wv * VISW;
  if (bm_ok) {
    for (int j = lane; j < VISW; j += 64) visW[j] = 0u;
    if (lane == 0 && active) visW[(unsigned)f0 >> 5] = 1u << (f0 & 31);
  }

  // Speculative triplet issued pre-barrier (flies during the chain phase).
  int3 t0 = *reinterpret_cast<const int3*>(nb + 3 * (size_t)row.x);
  int3 t1 = *reinterpret_cast<const int3*>(nb + 3 * (size_t)row.y);
  int3 t2 = *reinterpret_cast<const int3*>(nb + 3 * (size_t)row.z);

  // ---- Phase A0: wave 0 computes the block's 16 carry chains -------------
  if (wv == 0 && lane < WPB && (w0 + lane) < num_walks) {
    uint32_t ka, kb;
    tf2x32(0u, 42u, 0u, (uint32_t)(w0 + lane), ka, kb);  // k_0
    keysL[lane * KSTRIDE + 0] = make_uint2(ka, kb);
#pragma clang loop unroll(disable)
    for (int c2 = 1; c2 < CH; ++c2) {
      tf2x32(ka, kb, 0u, 0u, ka, kb);
      keysL[lane * KSTRIDE + c2] = make_uint2(ka, kb);
    }
  }
  __syncthreads();   // the only barrier: keys ready

  if (!active) return;

  // ---- Per-step key/code: lane c = step c (wave-local) -------------------
  const uint2 mykey = keysL[wv * KSTRIDE + lane];
  const uint32_t mka = mykey.x, mkb = mykey.y;
  uint32_t mycode;
  {
    uint32_t k1a, k1b, hi, lo;
    tf2x32(mka, mkb, 0u, 1u, k1a, k1b);   // k1 = split(k,4)[1]
    randbits(k1a, k1b, hi, lo);
    mycode = pick_code(hi, lo);
  }

  uint32_t extka = 0, extkb = 0;
  int extc = -1;     // lazy chain extension beyond CH (only after backtracks)
  auto get_key = [&](int idx, uint32_t& ra, uint32_t& rb) {
    if (idx < CH) {
      ra = (uint32_t)__shfl((int)mka, idx);
      rb = (uint32_t)__shfl((int)mkb, idx);
    } else {
      if (extc < 0) {
        extka = (uint32_t)__shfl((int)mka, CH - 1);
        extkb = (uint32_t)__shfl((int)mkb, CH - 1);
        extc = CH - 1;
      }
      while (extc < idx) { tf2x32(extka, extkb, 0u, 0u, extka, extkb); ++extc; }
      ra = extka; rb = extkb;
    }
  };

  int seqr = (lane == 0) ? f0 : -1;       // lane t = seq[t]
  int i = 1, bs = 1, c = 0;

  if (bm_ok) {
    // ============ global rows (VMEM triplet) + LDS bitmap =================
    while (i <= L) {
      const int idx = c; ++c;
      const int n0 = row.x, n1 = row.y, n2 = row.z;
      // 3 wave-uniform DS reads (broadcast, conflict-free).
      const uint32_t wv0 = visW[(unsigned)n0 >> 5];
      const uint32_t wv1 = visW[(unsigned)n1 >> 5];
      const uint32_t wv2 = visW[(unsigned)n2 >> 5];
      const uint32_t u0 = ((wv0 >> (n0 & 31)) & 1u) ^ 1u;
      const uint32_t u1 = ((wv1 >> (n1 & 31)) & 1u) ^ 1u;
      const uint32_t u2 = ((wv2 >> (n2 & 31)) & 1u) ^ 1u;
      const uint32_t cnt = u0 + u1 + u2;

      int to_add, sel;
      if (__builtin_expect(cnt == 0, 0)) {
        // ---- rare backtrack path (live hashing, bit-exact) ----
        sel = -1;
        uint32_t kia, kib;
        get_key(idx, kia, kib);
        uint32_t kka, kkb;
        tf2x32(kia, kib, 0u, 2u, kka, kkb);  // k2
        bool found = false;
        int ta = 0, bsc = bs;
        while (!found && i > bsc) {
          uint32_t ca, cb, kpa, kpb;
          tf2x32(kka, kkb, 0u, 0u, ca, cb);
          tf2x32(kka, kkb, 0u, 1u, kpa, kpb);
          const int back = __shfl(seqr, i - bsc - 1);
          const int3 br = *reinterpret_cast<const int3*>(nb + 3 * (size_t)back);
          const uint32_t e0 = ((visW[(unsigned)br.x >> 5] >> (br.x & 31)) & 1u) ^ 1u;
          const uint32_t e1 = ((visW[(unsigned)br.y >> 5] >> (br.y & 31)) & 1u) ^ 1u;
          const uint32_t e2 = ((visW[(unsigned)br.z >> 5] >> (br.z & 31)) & 1u) ^ 1u;
          const uint32_t bc = e0 + e1 + e2;
          if (bc > 0) {
            uint32_t bhi, blo;
            randbits(kpa, kpb, bhi, blo);
            const uint32_t bcode = pick_code(bhi, blo);
            const uint32_t r3 = bcode & 3u, r2 = (bcode >> 2) & 1u;
            const uint32_t t2v = (bc == 3 ? r3 : (bc == 2 ? r2 : 0)) + 1;
            ta = (e0 == t2v) ? br.x : ((e0 + e1 == t2v) ? br.y : br.z);
            found = true;
          } else {
            bsc += 2;
          }
          kka = ca; kkb = cb;
        }
        if (found) {
          to_add = ta;
          const int i_new = i - bsc;
          seqr = (lane >= i_new && lane < i) ? to_add : seqr;  // splat
          bs = bsc; i = i_new;
        } else {
          uint32_t k3a, k3b, rhi, rlo;
          tf2x32(kia, kib, 0u, 3u, k3a, k3b);  // k3
          randbits(k3a, k3b, rhi, rlo);
          to_add = (int)r_generic(rhi, rlo, (uint32_t)N);
          bs = 1;
        }
        if (lane == 0)
          visW[(unsigned)to_add >> 5] |= 1u << (to_add & 31);
        seqr = (lane == i) ? to_add : seqr;
        ++i;
        row = *reinterpret_cast<const int3*>(nb + 3 * (size_t)to_add);
      } else {
        // ---- common path ----
        uint32_t code;
        if (__builtin_expect(idx >= CH, 0)) {   // beyond cached steps (rare)
          uint32_t ia, ib, k1a, k1b, hi, lo;
          get_key(idx, ia, ib);
          tf2x32(ia, ib, 0u, 1u, k1a, k1b);
          randbits(k1a, k1b, hi, lo);
          code = pick_code(hi, lo);
        } else {
          code = (uint32_t)__builtin_amdgcn_readlane((int)mycode, idx);
        }
        const uint32_t r3 = code & 3u, r2 = (code >> 2) & 1u;
        const uint32_t target = (cnt == 3 ? r3 : (cnt == 2 ? r2 : 0)) + 1;
        sel = (u0 == target) ? 0 : ((u0 + u1 == target) ? 1 : 2);
        to_add = (sel == 0) ? n0 : ((sel == 1) ? n1 : n2);
        // set bit reusing this iter's word (DS in-order within wave).
        const uint32_t wsel = (sel == 0) ? wv0 : ((sel == 1) ? wv1 : wv2);
        if (lane == 0)
          visW[(unsigned)to_add >> 5] = wsel | (1u << (to_add & 31));
        seqr = (lane == i) ? to_add : seqr;
        bs = 1; ++i;
        row = (sel == 0) ? t0 : ((sel == 1) ? t1 : t2);
      }
      // Issue next speculative triplet (VMEM pipe; decide overlaps flight).
      t0 = *reinterpret_cast<const int3*>(nb + 3 * (size_t)row.x);
      t1 = *reinterpret_cast<const int3*>(nb + 3 * (size_t)row.y);
      t2 = *reinterpret_cast<const int3*>(nb + 3 * (size_t)row.z);
    }
  } else {
    // ============ hist fallback for N > 65536 (verified R5/R8) ============
    int hist  = (lane == 0) ? f0 : -1;
    int hist2 = -1;
    while (i <= L) {
      const int idx = c; ++c;
      const bool deep = (idx >= CH);
      const int n0 = row.x, n1 = row.y, n2 = row.z;
      int v0 = __any(hist == n0), v1 = __any(hist == n1), v2 = __any(hist == n2);
      if (deep) {
        v0 |= __any(hist2 == n0); v1 |= __any(hist2 == n1); v2 |= __any(hist2 == n2);
      }
      const int u0 = 1 - v0, u1 = 1 - v1, u2 = 1 - v2;
      const int cnt = u0 + u1 + u2;

      int to_add;
      bool hit = false;
      int bsf = bs;
      if (cnt > 0) {
        uint32_t code;
        if (deep) {
          uint32_t ia, ib, k1a, k1b, hi, lo;
          get_key(idx, ia, ib);
          tf2x32(ia, ib, 0u, 1u, k1a, k1b);
          randbits(k1a, k1b, hi, lo);
          code = pick_code(hi, lo);
        } else {
          code = (uint32_t)__builtin_amdgcn_readlane((int)mycode, idx);
        }
        const int r3 = (int)(code & 3u), r2 = (int)((code >> 2) & 1u);
        const int target = (cnt == 3 ? r3 : (cnt == 2 ? r2 : 0)) + 1;
        to_add = (u0 == target) ? n0 : ((u0 + u1 == target) ? n1 : n2);
      } else {
        uint32_t kia, kib;
        get_key(idx, kia, kib);
        uint32_t kka, kkb;
        tf2x32(kia, kib, 0u, 2u, kka, kkb);
        bool found = false;
        int ta = 0, bsc = bs;
        while (!found && i > bsc) {
          uint32_t ca, cb, kpa, kpb;
          tf2x32(kka, kkb, 0u, 0u, ca, cb);
          tf2x32(kka, kkb, 0u, 1u, kpa, kpb);
          const int back = __shfl(seqr, i - bsc - 1);
          const int3 br = *reinterpret_cast<const int3*>(nb + 3 * (size_t)back);
          int w0m = __any(hist == br.x), w1m = __any(hist == br.y), w2m = __any(hist == br.z);
          if (deep) {
            w0m |= __any(hist2 == br.x); w1m |= __any(hist2 == br.y); w2m |= __any(hist2 == br.z);
          }
          const int e0 = 1 - w0m, e1 = 1 - w1m, e2 = 1 - w2m;
          const int bc = e0 + e1 + e2;
          if (bc > 0) {
            uint32_t bhi, blo;
            randbits(kpa, kpb, bhi, blo);
            const uint32_t bcode = pick_code(bhi, blo);
            const int r3 = (int)(bcode & 3u), r2 = (int)((bcode >> 2) & 1u);
            const int t2v = (bc == 3 ? r3 : (bc == 2 ? r2 : 0)) + 1;
            ta = (e0 == t2v) ? br.x : ((e0 + e1 == t2v) ? br.y : br.z);
            found = true;
          } else {
            bsc += 2;
          }
          kka = ca; kkb = cb;
        }
        if (found) {
          to_add = ta; hit = true; bsf = bsc;
        } else {
          uint32_t k3a, k3b, rhi, rlo;
          tf2x32(kia, kib, 0u, 3u, k3a, k3b);
          randbits(k3a, k3b, rhi, rlo);
          to_add = (int)r_generic(rhi, rlo, (uint32_t)N);
        }
      }

      int i_new, up;
      if (hit) { i_new = i - bsf; bs = bsf; up = i - 1; }
      else     { i_new = i;       bs = 1;   up = i; }
      seqr = (lane >= i_new && lane <= up) ? to_add : seqr;

      const int slot = idx + 1;
      if (slot < CH)          hist  = (lane == slot)      ? to_add : hist;
      else if (slot < 2 * CH) hist2 = (lane == slot - CH) ? to_add : hist2;

      i = i_new + 1;
      row = *reinterpret_cast<const int3*>(nb + 3 * (size_t)to_add);
    }
  }

  // ---- Epilogue: lane t holds seq[t] ------------------------------------
  const float cx = xb[3 * (size_t)f0 + 0];
  const float cy = xb[3 * (size_t)f0 + 1];
  const float cz = xb[3 * (size_t)f0 + 2];
  if (lane < Lp1) {
    const int node = seqr;
    float3 v;
    v.x = xb[3 * (size_t)node + 0] - cx;
    v.y = xb[3 * (size_t)node + 1] - cy;
    v.z = xb[3 * (size_t)node + 2] - cz;
    *reinterpret_cast<float3*>(out + ((size_t)w * Lp1 + lane) * 3) = v;
  }
}

}  // namespace

extern "C" void kernel_launch(void* const* d_in, const int* in_sizes, int n_in,
                              void* d_out, int out_size, void* d_ws, size_t ws_size,
                              hipStream_t stream) {
  const float* xyz     = (const float*)d_in[0];
  const int*   nbrs    = (const int*)d_in[1];
  const int*   centers = (const int*)d_in[2];
  const int*   n_faces = (const int*)d_in[3];
  const int*   seq_len = (const int*)d_in[4];
  float* out = (float*)d_out;

  const int s0 = in_sizes[0];                  // B*N*3
  const int num_walks = in_sizes[2];           // B*G
  const int Lp1 = out_size / (3 * num_walks);  // seq_len+1

  const int blocks = (num_walks + WPB - 1) / WPB;
  walk_kernel<<<blocks, WPB * 64, 0, stream>>>(
      xyz, nbrs, centers, n_faces, seq_len, out, s0, num_walks, Lp1);
}